// Round 12
// baseline (1479.498 us; speedup 1.0000x reference)
//
#include <hip/hip_runtime.h>
#include <math.h>

// Problem dims (fixed by reference)
#define BB   8
#define TT   2048
#define CIN  512
#define DD   1024
#define MM   (BB * TT)     // 16384 rows for the GEMMs

// K1 GEMM: 64x64 block tile, 128 threads (2 waves), 8x4 dual micro-tile.
// Microtile/BK/loop structure FROZEN (R1 spill, R2 dbuf, R7 lgkm, R9 BK=32
// all regressed).  R12 probe: OccupancyPercent read only 21.5% (~7 waves/CU)
// though resources allow ~20 — hypothesis: 4-wave barrier skew + low block
// residency.  128-thread blocks halve barrier width (2 waves) and allow
// 8 blocks/CU (__launch_bounds__(128,4): 4 waves/SIMD min -> VGPR cap 128).
// Per-thread FMA work identical; w-staging 4 float4s/thread (was 2); x same.
// W re-fetch doubles but W=8MB is L2-resident (HBM at 7%, irrelevant).
constexpr int BM = 64;
constexpr int BN = 64;
constexpr int BK = 16;

// K2+K3 fused scan+LN (FROZEN at the R11 form): 2 features/thread, float4
// interleaved ab quads, h_post never hits HBM, lgkm-only barriers, R7 reduce.
// Plateau established: R5/R6/R7/R10/R11 variants all within +-2% (~155us).
// NCHUNK=32 minimizes warm amplification (R8); WARM=64 contamination < 1e-4.
#define NCHUNK 32
#define CLEN   (TT / NCHUNK)   // 64
#define WARM   64
#define PF     8

// LDS-only barrier: waits LDS ops, leaves global loads/stores in flight.
// Use ONLY where loaded registers are not consumed immediately after the
// barrier (k23 yes, k1 no — round-7 lesson).
__device__ __forceinline__ void lgkm_bar() {
    asm volatile("s_waitcnt lgkmcnt(0)" ::: "memory");
    __builtin_amdgcn_s_barrier();
}

// softplus(z) = logaddexp(z, 0) — matches jax.nn.softplus / np.logaddexp
__device__ __forceinline__ float softplus_f(float z) {
    return fmaxf(z, 0.f) + log1pf(expf(-fabsf(z)));
}

// K1: fused dual GEMM  zd = x@Wd, zb = x@Wb  (+bias)  →  interleaved (a,b)
__global__ __launch_bounds__(128, 4) void k1_gemm_act(
    const float* __restrict__ x,      // [MM, CIN]
    const float* __restrict__ Wd,     // [CIN, DD]
    const float* __restrict__ Wb,     // [CIN, DD]
    const float* __restrict__ bd,     // [DD]
    const float* __restrict__ bb,     // [DD]
    const float* __restrict__ A_log,  // [DD]
    float* __restrict__ ab_out)       // [MM, 2*DD] interleaved quads
{
    // xs transposed: xs[k][m] -> x-fragments are broadcast b128 reads;
    // scatter stores 2-way (free).  Wave-level read patterns are identical
    // to the proven 256-thread layout (tx/ty per-wave ranges unchanged).
    __shared__ float xs[BK][BM + 4];    // 16x68x4 = 4352 B
    __shared__ float wds[BK][BN];       // 4096 B
    __shared__ float wbs[BK][BN];       // 4096 B  -> 12544 B total

    const int tid = threadIdx.x;
    const int n0  = blockIdx.x * BN;
    const int m0  = blockIdx.y * BM;
    const int tx  = tid & 15;          // col group: 4 cols each
    const int ty  = tid >> 4;          // row group: 8 rows each (0..7)

    // staging indices
    const int lm = tid >> 1;           // 0..63   x row
    const int lk = (tid & 1) * 8;      // 0 or 8  (two float4 = 8 k)
    const int wr = tid >> 4;           // 0..7    w row (and wr+8)
    const int wc = (tid & 15) * 4;     // 0..60   w col

    float accd[8][4], accb[8][4];
#pragma unroll
    for (int r = 0; r < 8; ++r)
#pragma unroll
        for (int c = 0; c < 4; ++c) { accd[r][c] = 0.f; accb[r][c] = 0.f; }

    // ---- preload tile 0 into registers ----
    const float* xp  = x + (size_t)(m0 + lm) * CIN + lk;
    const float* wdp = Wd + (size_t)wr * DD + n0 + wc;
    const float* wbp = Wb + (size_t)wr * DD + n0 + wc;
    float4 xva = *(const float4*)(xp);
    float4 xvb = *(const float4*)(xp + 4);
    float4 wd0 = *(const float4*)(wdp);
    float4 wd1 = *(const float4*)(wdp + (size_t)8 * DD);
    float4 wb0 = *(const float4*)(wbp);
    float4 wb1 = *(const float4*)(wbp + (size_t)8 * DD);

    for (int k0 = 0; k0 < CIN; k0 += BK) {
        __syncthreads();   // previous tile's compute done
        xs[lk + 0][lm] = xva.x;  xs[lk + 1][lm] = xva.y;
        xs[lk + 2][lm] = xva.z;  xs[lk + 3][lm] = xva.w;
        xs[lk + 4][lm] = xvb.x;  xs[lk + 5][lm] = xvb.y;
        xs[lk + 6][lm] = xvb.z;  xs[lk + 7][lm] = xvb.w;
        *(float4*)&wds[wr][wc]     = wd0;
        *(float4*)&wds[wr + 8][wc] = wd1;
        *(float4*)&wbs[wr][wc]     = wb0;
        *(float4*)&wbs[wr + 8][wc] = wb1;
        __syncthreads();

        // issue next tile's global loads (in flight during compute)
        const int kn = k0 + BK;
        if (kn < CIN) {
            xva = *(const float4*)(xp + kn);
            xvb = *(const float4*)(xp + kn + 4);
            wd0 = *(const float4*)(wdp + (size_t)kn * DD);
            wd1 = *(const float4*)(wdp + (size_t)(kn + 8) * DD);
            wb0 = *(const float4*)(wbp + (size_t)kn * DD);
            wb1 = *(const float4*)(wbp + (size_t)(kn + 8) * DD);
        }

#pragma unroll
        for (int kk = 0; kk < BK; ++kk) {
            float4 xa  = *(const float4*)&xs[kk][ty * 8];
            float4 xa2 = *(const float4*)&xs[kk][ty * 8 + 4];
            float4 d0  = *(const float4*)&wds[kk][tx * 4];
            float4 c0  = *(const float4*)&wbs[kk][tx * 4];
            float xr[8] = {xa.x, xa.y, xa.z, xa.w, xa2.x, xa2.y, xa2.z, xa2.w};
            float wd[4] = {d0.x, d0.y, d0.z, d0.w};
            float wb[4] = {c0.x, c0.y, c0.z, c0.w};
#pragma unroll
            for (int r = 0; r < 8; ++r) {
                const float xi = xr[r];
#pragma unroll
                for (int c = 0; c < 4; ++c) {
                    accd[r][c] = fmaf(xi, wd[c], accd[r][c]);
                    accb[r][c] = fmaf(xi, wb[c], accb[r][c]);
                }
            }
        }
    }

    // ---- epilogue: interleaved quads (a0,a1,b0,b1)(a2,a3,b2,b3) ----
    const int nc0 = n0 + tx * 4;
    float4 bdq = *(const float4*)(bd + nc0);
    float4 bbq = *(const float4*)(bb + nc0);
    float4 alq = *(const float4*)(A_log + nc0);
    const float* bdv = (const float*)&bdq;
    const float* bbv = (const float*)&bbq;
    float Aq[4] = {expf(alq.x), expf(alq.y), expf(alq.z), expf(alq.w)};

#pragma unroll
    for (int r = 0; r < 8; ++r) {
        const int m = m0 + ty * 8 + r;
        float av[4], bv[4];
#pragma unroll
        for (int j = 0; j < 4; ++j) {
            float zd    = accd[r][j] + bdv[j];
            float delta = softplus_f(zd);
            float zb    = accb[r][j] + bbv[j];
            av[j] = expf(-delta * Aq[j]);
            bv[j] = delta * zb;
        }
        float* abp = ab_out + (size_t)m * (2 * DD) + 2 * nc0;
        *(float4*)(abp)     = make_float4(av[0], av[1], bv[0], bv[1]);
        *(float4*)(abp + 4) = make_float4(av[2], av[3], bv[2], bv[3]);
    }
}

// ---- fused scan + LayerNorm (512 threads, 2 features/thread) ----
// Per output batch (R7 reduce, 2 lgkm-only barriers):
//   scan PF steps from float4 ab quads (spikes inline, h stashed in regs)
//   pre-sum (sum, sumsq) per step -> trans[tid][0..15]   (pad 17: bank-free)
//   PREFETCH next batch (global loads stay in flight across both barriers)
//   bar1 -> 512-thread column sum (16 rows/thread at i2*32+rs) + 5-stage shfl
//           over 32 partials -> red[16]
//   bar2 -> all threads read red[] (broadcast) and compute mu/inv
//           redundantly-identically, LN writes
// Hazards: trans reads (pre-bar2) vs next trans writes (post-bar2) OK; red
// write (pre-bar2) vs reads (post-bar2) OK; red reads retired by reader's
// lgkmcnt(0) at next bar1, before next red write OK.  Branches block-uniform.

#define PREFETCH(ABV)                                                     \
    {                                                                     \
        _Pragma("unroll")                                                 \
        for (int j = 0; j < PF; ++j)                                      \
            ABV[j] = *(const float4*)(abp + (size_t)j * (2 * DD));        \
        abp += (size_t)PF * (2 * DD);                                     \
    }

#define WARM_SLOT(ABV)                                                    \
    {                                                                     \
        _Pragma("unroll")                                                 \
        for (int j = 0; j < PF; ++j) {                                    \
            h.x = fmaf(ABV[j].x, h.x, ABV[j].z);                          \
            h.y = fmaf(ABV[j].y, h.y, ABV[j].w);                          \
            h.x = ((h.x - th.x) > 0.f) ? 0.f : h.x;                       \
            h.y = ((h.y - th.y) > 0.f) ? 0.f : h.y;                       \
        }                                                                 \
    }

#define OUT_SLOT(ABV, PFOK)                                               \
    {                                                                     \
        float2 hj[PF];                                                    \
        _Pragma("unroll")                                                 \
        for (int j = 0; j < PF; ++j) {                                    \
            h.x = fmaf(ABV[j].x, h.x, ABV[j].z);                          \
            h.y = fmaf(ABV[j].y, h.y, ABV[j].w);                          \
            const bool kx = (h.x - th.x) > 0.f;                           \
            const bool ky = (h.y - th.y) > 0.f;                           \
            *(float2*)(sp + (size_t)j * DD) =                             \
                make_float2(kx ? 1.f : 0.f, ky ? 1.f : 0.f);              \
            h.x = kx ? 0.f : h.x;                                         \
            h.y = ky ? 0.f : h.y;                                         \
            hj[j] = h;                                                    \
        }                                                                 \
        sp += (size_t)PF * DD;                                            \
        _Pragma("unroll")                                                 \
        for (int j = 0; j < PF; ++j) {                                    \
            trans[tid][j]      = hj[j].x + hj[j].y;                       \
            trans[tid][j + PF] = fmaf(hj[j].x, hj[j].x,                   \
                                      hj[j].y * hj[j].y);                 \
        }                                                                 \
        if (PFOK) PREFETCH(ABV)                                           \
        lgkm_bar();                                                       \
        {                                                                 \
            float p = 0.f;                                                \
            _Pragma("unroll")                                             \
            for (int i2 = 0; i2 < 16; ++i2)                               \
                p += trans[i2 * 32 + rs][rq];                             \
            p += __shfl_down(p, 16);                                      \
            p += __shfl_down(p, 8);                                       \
            p += __shfl_down(p, 4);                                       \
            p += __shfl_down(p, 2);                                       \
            p += __shfl_down(p, 1);                                       \
            if (rs == 0) red[rq] = p;                                     \
        }                                                                 \
        lgkm_bar();                                                       \
        float mu_[PF], inv_[PF];                                          \
        _Pragma("unroll")                                                 \
        for (int j = 0; j < PF; ++j) {                                    \
            const float mu  = red[j] * (1.0f / DD);                       \
            const float var =                                             \
                fmaxf(red[j + PF] * (1.0f / DD) - mu * mu, 0.f);          \
            mu_[j]  = mu;                                                 \
            inv_[j] = 1.0f / sqrtf(var + 1e-5f);                          \
        }                                                                 \
        _Pragma("unroll")                                                 \
        for (int j = 0; j < PF; ++j) {                                    \
            float2 o;                                                     \
            o.x = (hj[j].x - mu_[j]) * inv_[j] * g.x + be.x;              \
            o.y = (hj[j].y - mu_[j]) * inv_[j] * g.y + be.y;              \
            *(float2*)(op + (size_t)j * DD) = o;                          \
        }                                                                 \
        op += (size_t)PF * DD;                                            \
    }

__global__ __launch_bounds__(512) void k23_scan_ln(
    const float* __restrict__ ab,     // [BB, TT, 2*DD] interleaved quads
    const float* __restrict__ thr,    // [DD]
    const float* __restrict__ gamma,  // [DD]
    const float* __restrict__ beta,   // [DD]
    float* __restrict__ out,          // [BB, TT, DD]
    float* __restrict__ spikes)       // [BB, TT, DD]
{
    const int tid   = threadIdx.x;     // 0..511 — two features per thread
    const int d0    = tid * 2;
    const int chunk = blockIdx.x;      // 0..31
    const int batch = blockIdx.y;      // 0..7
    const int rq    = tid >> 5;        // 0..15: quantity (0..7 sum, 8..15 ssq)
    const int rs    = tid & 31;        // 0..31: summer index within quantity

    const float2 th = *(const float2*)(thr + d0);
    const float2 g  = *(const float2*)(gamma + d0);
    const float2 be = *(const float2*)(beta + d0);

    const int t0    = chunk * CLEN;
    const int nwarm = (t0 < WARM) ? t0 : WARM;   // 0 or 64; chunks 0-1 exact
    const int tw    = t0 - nwarm;
    const int nwb   = nwarm / PF;                // 0 or 8
    const int ntot  = nwb + CLEN / PF;           // 8 or 16 (even)

    const float* abp = ab + (size_t)batch * TT * (2 * DD)
                          + (size_t)tw * (2 * DD) + 4 * tid;
    const size_t rowbase = (size_t)batch * TT * DD + d0;
    float* op = out    + rowbase + (size_t)t0 * DD;
    float* sp = spikes + rowbase + (size_t)t0 * DD;

    __shared__ float trans[512][17];   // 34816 B, pad 17 -> bank-conflict-free
    __shared__ float red[2 * PF];

    float4 ab0[PF], ab1[PF];
    PREFETCH(ab0)
    PREFETCH(ab1)

    float2 h = make_float2(0.f, 0.f);
    for (int i = 0; i < ntot; i += 2) {
        if (i >= nwb) OUT_SLOT(ab0, i + 2 < ntot)
        else { WARM_SLOT(ab0) PREFETCH(ab0) }

        if (i + 1 >= nwb) OUT_SLOT(ab1, i + 3 < ntot)
        else { WARM_SLOT(ab1) PREFETCH(ab1) }
    }
}

extern "C" void kernel_launch(void* const* d_in, const int* in_sizes, int n_in,
                              void* d_out, int out_size, void* d_ws, size_t ws_size,
                              hipStream_t stream) {
    const float* x     = (const float*)d_in[0];
    const float* Wd    = (const float*)d_in[1];
    const float* bd    = (const float*)d_in[2];
    const float* Wb    = (const float*)d_in[3];
    const float* bb    = (const float*)d_in[4];
    const float* A_log = (const float*)d_in[5];
    const float* thr   = (const float*)d_in[6];
    const float* gamma = (const float*)d_in[7];
    const float* beta  = (const float*)d_in[8];

    float* out    = (float*)d_out;                    // [MM, DD] LN output
    float* spikes = out + (size_t)MM * DD;            // [MM, DD]
    float* ab_ws  = (float*)d_ws;                     // [MM, 2*DD] interleaved

    dim3 g1(DD / BN, MM / BM);                        // (16, 256) = 4096 blocks
    k1_gemm_act<<<g1, 128, 0, stream>>>(x, Wd, Wb, bd, bb, A_log, ab_ws);

    dim3 g2(NCHUNK, BB);                              // (32, 8) = 256 blocks, 1/CU
    k23_scan_ln<<<g2, 512, 0, stream>>>(ab_ws, thr, gamma, beta, out, spikes);
}